// Round 1
// baseline (2059.351 us; speedup 1.0000x reference)
//
#include <hip/hip_runtime.h>
#include <math.h>

#define BB 4
#define CIN 3
#define HIM 224
#define WIM 224
#define PS 16
#define DIM 256
#define HEADS 8
#define HD 32
#define HP 14
#define WP 14
#define NP 196
#define PIXN (HIM*WIM)   // 50176

// ---------------- v = conv3x3(x) + vb  -> [B, DIM, 224, 224] ----------------
__global__ __launch_bounds__(256) void k_vconv(const float* __restrict__ x,
        const float* __restrict__ vw, const float* __restrict__ vb,
        float* __restrict__ v)
{
    int tid = blockIdx.x * 256 + threadIdx.x;          // 12,845,056 total
    int x0 = (tid % (WIM/4)) * 4;
    int t  = tid / (WIM/4);
    int y  = t % HIM; t /= HIM;
    int c  = t % DIM; int b = t / DIM;
    float bias = vb[c];
    float a0 = bias, a1 = bias, a2 = bias, a3 = bias;
    const float* wbase = vw + c * CIN * 9;
    for (int cin = 0; cin < CIN; ++cin) {
        const float* xpl = x + ((size_t)(b*CIN + cin) * HIM) * WIM;
        const float* w9  = wbase + cin * 9;
        #pragma unroll
        for (int dy = 0; dy < 3; ++dy) {
            int yy = y + dy - 1;
            if (yy < 0 || yy >= HIM) continue;
            const float* row = xpl + yy * WIM;
            float r[6];
            #pragma unroll
            for (int i = 0; i < 6; ++i) {
                int xx = x0 - 1 + i;
                r[i] = (xx >= 0 && xx < WIM) ? row[xx] : 0.f;
            }
            float w0 = w9[dy*3+0], w1 = w9[dy*3+1], w2 = w9[dy*3+2];
            a0 += w0*r[0] + w1*r[1] + w2*r[2];
            a1 += w0*r[1] + w1*r[2] + w2*r[3];
            a2 += w0*r[2] + w1*r[3] + w2*r[4];
            a3 += w0*r[3] + w1*r[4] + w2*r[5];
        }
    }
    *(float4*)(v + ((size_t)(b*DIM + c)*HIM + y)*WIM + x0) = make_float4(a0,a1,a2,a3);
}

// ------------- xe[b,n,c] = patch-embed conv (stride 16) + pb ---------------
__global__ __launch_bounds__(256) void k_patch(const float* __restrict__ x,
        const float* __restrict__ pw, const float* __restrict__ pb,
        float* __restrict__ xe)
{
    __shared__ __align__(16) float px[CIN*PS*PS];       // 768 floats
    int b = blockIdx.x / NP, n = blockIdx.x % NP;
    int hp = n / WP, wp = n % WP;
    for (int i = threadIdx.x; i < CIN*PS*PS; i += 256) {
        int cin = i >> 8, rem = i & 255;
        int ki = rem >> 4, kj = rem & 15;
        px[i] = x[((size_t)(b*CIN + cin)*HIM + hp*PS + ki)*WIM + wp*PS + kj];
    }
    __syncthreads();
    int c = threadIdx.x;
    const float* wrow = pw + (size_t)c * (CIN*PS*PS);
    float acc = pb[c];
    for (int i = 0; i < CIN*PS*PS; i += 4) {
        float4 wv = *(const float4*)(wrow + i);
        float4 xv = *(const float4*)(px + i);
        acc += wv.x*xv.x + wv.y*xv.y + wv.z*xv.z + wv.w*xv.w;
    }
    xe[(size_t)(b*NP + n)*DIM + c] = acc;
}

// ---- q,k [bh, n, 32] = xe @ qk_w^T split (row j<256 -> q, else k) ---------
__global__ __launch_bounds__(512) void k_qk(const float* __restrict__ xe,
        const float* __restrict__ qkw, float* __restrict__ q, float* __restrict__ kk)
{
    __shared__ __align__(16) float xr[DIM];
    int bn = blockIdx.x;                                 // 784
    for (int i = threadIdx.x; i < DIM; i += 512) xr[i] = xe[(size_t)bn*DIM + i];
    __syncthreads();
    int j = threadIdx.x;                                 // 0..511
    const float* wrow = qkw + (size_t)j * DIM;
    float acc = 0.f;
    for (int i = 0; i < DIM; i += 4) {
        float4 wv = *(const float4*)(wrow + i);
        float4 xv = *(const float4*)(xr + i);
        acc += wv.x*xv.x + wv.y*xv.y + wv.z*xv.z + wv.w*xv.w;
    }
    int s = j >> 8, h = (j >> 5) & 7, d = j & 31;
    int b = bn / NP, n = bn % NP;
    float* dst = s ? kk : q;
    dst[((size_t)(b*HEADS + h)*NP + n)*HD + d] = acc;
}

// ------------- attn[row, m] = softmax_m( q.k * scale ), row = (b,h,n) ------
__global__ __launch_bounds__(256) void k_attn(const float* __restrict__ q,
        const float* __restrict__ kk, float* __restrict__ attn)
{
    int wid = threadIdx.x >> 6, lane = threadIdx.x & 63;
    int row = blockIdx.x * 4 + wid;                      // [0, 6272)
    const float* qrow = q + (size_t)row * HD;
    float qr[HD];
    #pragma unroll
    for (int i = 0; i < HD; ++i) qr[i] = qrow[i];
    int bh = row / NP;
    const float* kbase = kk + (size_t)bh * NP * HD;
    float s[4];
    #pragma unroll
    for (int t = 0; t < 4; ++t) {
        int m = lane + t*64;
        if (m < NP) {
            const float* krow = kbase + (size_t)m * HD;
            float a = 0.f;
            #pragma unroll
            for (int i = 0; i < HD; ++i) a += qr[i]*krow[i];
            s[t] = a * 0.17677669529663689f;             // 32^-0.5
        } else s[t] = -1e30f;
    }
    float mx = fmaxf(fmaxf(s[0], s[1]), fmaxf(s[2], s[3]));
    #pragma unroll
    for (int off = 32; off > 0; off >>= 1) mx = fmaxf(mx, __shfl_xor(mx, off));
    float e[4]; float sum = 0.f;
    #pragma unroll
    for (int t = 0; t < 4; ++t) { e[t] = __expf(s[t] - mx); sum += e[t]; }
    #pragma unroll
    for (int off = 32; off > 0; off >>= 1) sum += __shfl_xor(sum, off);
    float inv = 1.f / sum;
    float* arow = attn + (size_t)row * NP;
    #pragma unroll
    for (int t = 0; t < 4; ++t) {
        int m = lane + t*64;
        if (m < NP) arow[m] = e[t]*inv;
    }
}

// ------ out_folded = fold( attn @ unfold(v) ), written directly to d_out ---
// per (b,h): OF[n, d] = sum_m A[n,m] * v[b, 32h + d/256, pix(m, d%256)]
// block = (bh, ntile in 7 of 28 rows, dblk in 16 of 512 d-cols)
__global__ __launch_bounds__(256) void k_av(const float* __restrict__ attn,
        const float* __restrict__ v, float* __restrict__ out)
{
    __shared__ __align__(16) float A[28][28];            // 3.1 KB
    __shared__ __align__(16) float V[28][512];           // 57.3 KB
    int gid = blockIdx.x;                                // 3584
    int dblk = gid & 15; int tmp = gid >> 4;
    int ntile = tmp % 7; int bh = tmp / 7;
    int b = bh >> 3, h = bh & 7;
    int r = threadIdx.x >> 6, j = threadIdx.x & 63;      // 4 n-groups x 64 d-lanes
    float acc[7][8];
    #pragma unroll
    for (int i = 0; i < 7; ++i)
        #pragma unroll
        for (int jj = 0; jj < 8; ++jj) acc[i][jj] = 0.f;

    const float* abase = attn + (size_t)(bh*NP + ntile*28) * NP;
    for (int mc = 0; mc < 7; ++mc) {
        for (int i = threadIdx.x; i < 784; i += 256) {   // A chunk [28 x 28]
            int rr = i / 28, cc = i % 28;
            A[rr][cc] = abase[(size_t)rr*NP + mc*28 + cc];
        }
        for (int i4 = threadIdx.x; i4 < 3584; i4 += 256) { // V chunk [28 x 512]
            int mm = i4 >> 7;
            int dl = (i4 & 127) << 2;
            int m  = mc*28 + mm;
            int c  = h*HD + dblk*2 + (dl >> 8);
            int p  = dl & 255;
            int y  = (m/14)*PS + (p >> 4);
            int xx = (m%14)*PS + (p & 15);
            *(float4*)&V[mm][dl] =
                *(const float4*)(v + ((size_t)(b*DIM + c)*HIM + y)*WIM + xx);
        }
        __syncthreads();
        #pragma unroll 4
        for (int mm = 0; mm < 28; ++mm) {
            float4 v0 = *(float4*)&V[mm][j*4];           // c' = dblk*2
            float4 v1 = *(float4*)&V[mm][256 + j*4];     // c' = dblk*2+1
            #pragma unroll
            for (int qq = 0; qq < 7; ++qq) {
                float a = A[r*7 + qq][mm];               // wave-broadcast
                acc[qq][0] += a*v0.x; acc[qq][1] += a*v0.y;
                acc[qq][2] += a*v0.z; acc[qq][3] += a*v0.w;
                acc[qq][4] += a*v1.x; acc[qq][5] += a*v1.y;
                acc[qq][6] += a*v1.z; acc[qq][7] += a*v1.w;
            }
        }
        __syncthreads();
    }
    int c0 = h*HD + dblk*2;
    int p  = j*4;
    int ki = p >> 4, kj = p & 15;
    #pragma unroll
    for (int qq = 0; qq < 7; ++qq) {
        int n  = ntile*28 + r*7 + qq;
        int y  = (n/14)*PS + ki, xx = (n%14)*PS + kj;
        float* d0 = out + ((size_t)(b*DIM + c0)*HIM + y)*WIM + xx;
        *(float4*)d0          = make_float4(acc[qq][0],acc[qq][1],acc[qq][2],acc[qq][3]);
        *(float4*)(d0 + PIXN) = make_float4(acc[qq][4],acc[qq][5],acc[qq][6],acc[qq][7]);
    }
}

// ------- in-place 1x1 proj on d_out: out[:,co,p] = W @ out[:,c,p] + b ------
// block = (b, 32-pixel tile); stages all 256 channels before overwriting.
__global__ __launch_bounds__(256) void k_proj(const float* __restrict__ pw,
        const float* __restrict__ pb, float* __restrict__ out)
{
    __shared__ __align__(16) float of[DIM][32];          // 32 KB
    __shared__ __align__(16) float wt[16][260];          // 16.6 KB (transposed W chunk, pad 260)
    int gid = blockIdx.x;                                // 4 * 1568
    int b  = gid / (PIXN/32);
    int p0 = (gid % (PIXN/32)) * 32;
    int t  = threadIdx.x;
    int ci = t >> 3;     // 0..31 -> co = ci*8 + q
    int pi = t & 7;      // 0..7  -> pix = p0 + pi*4 ..
    const float* obase = out + (size_t)b*DIM*PIXN + p0;
    for (int i4 = t; i4 < 2048; i4 += 256) {             // stage of[256][32]
        int c  = i4 >> 3;
        int pp = (i4 & 7) << 2;
        *(float4*)&of[c][pp] = *(const float4*)(obase + (size_t)c*PIXN + pp);
    }
    float acc[8][4];
    #pragma unroll
    for (int a = 0; a < 8; ++a)
        #pragma unroll
        for (int bq = 0; bq < 4; ++bq) acc[a][bq] = 0.f;

    for (int cb = 0; cb < 16; ++cb) {
        __syncthreads();                                 // of staged / prev chunk done
        for (int i = t; i < 4096; i += 256) {            // wt[cc][co], cc = cb*16..
            int co = i >> 4, cc = i & 15;
            wt[cc][co] = pw[(size_t)co*DIM + cb*16 + cc];
        }
        __syncthreads();
        #pragma unroll
        for (int cc = 0; cc < 16; ++cc) {
            int c = cb*16 + cc;
            float4 o4 = *(float4*)&of[c][pi*4];
            float4 w0 = *(float4*)&wt[cc][ci*8];
            float4 w1 = *(float4*)&wt[cc][ci*8 + 4];
            float wq[8] = {w0.x,w0.y,w0.z,w0.w,w1.x,w1.y,w1.z,w1.w};
            float op[4] = {o4.x,o4.y,o4.z,o4.w};
            #pragma unroll
            for (int a = 0; a < 8; ++a)
                #pragma unroll
                for (int bq = 0; bq < 4; ++bq) acc[a][bq] += wq[a]*op[bq];
        }
    }
    #pragma unroll
    for (int qq = 0; qq < 8; ++qq) {
        int co = ci*8 + qq;
        float bias = pb[co];
        *(float4*)(out + (size_t)(b*DIM + co)*PIXN + p0 + pi*4) =
            make_float4(acc[qq][0]+bias, acc[qq][1]+bias, acc[qq][2]+bias, acc[qq][3]+bias);
    }
}

extern "C" void kernel_launch(void* const* d_in, const int* in_sizes, int n_in,
                              void* d_out, int out_size, void* d_ws, size_t ws_size,
                              hipStream_t stream)
{
    const float* x   = (const float*)d_in[0];
    const float* pw  = (const float*)d_in[1];
    const float* pbb = (const float*)d_in[2];
    const float* qkw = (const float*)d_in[3];
    const float* vw  = (const float*)d_in[4];
    const float* vb  = (const float*)d_in[5];
    const float* prw = (const float*)d_in[6];
    const float* prb = (const float*)d_in[7];
    float* out = (float*)d_out;
    float* ws  = (float*)d_ws;

    const size_t n_v    = (size_t)BB*DIM*PIXN;       // 51,380,224
    const size_t n_attn = (size_t)BB*HEADS*NP*NP;    //  1,229,312
    const size_t n_xe   = (size_t)BB*NP*DIM;         //    200,704
    const size_t n_qk   = (size_t)BB*HEADS*NP*HD;    //    200,704
    const size_t need_b = (n_v + n_attn + n_xe + 2*n_qk) * sizeof(float);
    if (ws_size < need_b) return;                    // fail loudly (poison stays)

    float* v    = ws;
    float* attn = v + n_v;
    float* xe   = attn + n_attn;
    float* q    = xe + n_xe;
    float* kk   = q + n_qk;

    hipLaunchKernelGGL(k_vconv, dim3(50176), dim3(256), 0, stream, x, vw, vb, v);
    hipLaunchKernelGGL(k_patch, dim3(784),   dim3(256), 0, stream, x, pw, pbb, xe);
    hipLaunchKernelGGL(k_qk,    dim3(784),   dim3(512), 0, stream, xe, qkw, q, kk);
    hipLaunchKernelGGL(k_attn,  dim3(1568),  dim3(256), 0, stream, q, kk, attn);
    hipLaunchKernelGGL(k_av,    dim3(3584),  dim3(256), 0, stream, attn, v, out);
    hipLaunchKernelGGL(k_proj,  dim3(6272),  dim3(256), 0, stream, prw, prb, out);
}

// Round 2
// 801.196 us; speedup vs baseline: 2.5703x; 2.5703x over previous
//
#include <hip/hip_runtime.h>
#include <math.h>

#define BB 4
#define CIN 3
#define HIM 224
#define WIM 224
#define PS 16
#define DIM 256
#define HEADS 8
#define HD 32
#define HP 14
#define WP 14
#define NP 196
#define PIXN (HIM*WIM)   // 50176
#define NPAD 208         // 13*16 rows (M pad)
#define KPAD 224         // 7*32 cols (K pad)

typedef _Float16 half8 __attribute__((ext_vector_type(8)));
typedef _Float16 half4v __attribute__((ext_vector_type(4)));
typedef float f32x4 __attribute__((ext_vector_type(4)));

// ---------------- v = conv3x3(x) + vb  -> fp16 [B, DIM, 224, 224] ----------
// block: (b, cblk of 8 ch, ytile of 8 rows). LDS-staged x tile, zero-padded.
__global__ __launch_bounds__(256) void k_vconv(const float* __restrict__ x,
        const float* __restrict__ vw, const float* __restrict__ vb,
        _Float16* __restrict__ v)
{
    __shared__ __align__(16) float xs[CIN][10][240];   // col p holds x (p-4); 28.8 KB
    __shared__ float wl[8][28];
    __shared__ float bl[8];
    int gid = blockIdx.x;
    int yt = gid % 28; gid /= 28;
    int cb = gid % 32; int b = gid / 32;
    int y0 = yt * 8;
    int t = threadIdx.x;

    if (t < 224) { int ci = t / 28, k = t % 28; if (k < 27) wl[ci][k] = vw[(cb*8+ci)*27 + k]; }
    if (t < 8) bl[t] = vb[cb*8 + t];

    for (int i = t; i < 30*60; i += 256) {             // 30 (cin,row) x 60 f4-chunks
        int rr = i / 60, q4 = i % 60;
        int cin = rr / 10, r = rr % 10;
        int ys = y0 - 1 + r;
        float4 val = make_float4(0.f,0.f,0.f,0.f);
        if (q4 >= 1 && q4 <= 56 && ys >= 0 && ys < HIM)
            val = *(const float4*)(x + ((size_t)(b*CIN+cin)*HIM + ys)*WIM + (q4-1)*4);
        *(float4*)&xs[cin][r][q4*4] = val;
    }
    __syncthreads();

    int ci = t >> 5, xg = t & 31;
    if (xg >= 28) return;
    float w[27];
    #pragma unroll
    for (int k = 0; k < 27; ++k) w[k] = wl[ci][k];
    float bias = bl[ci];
    int c = cb*8 + ci;
    _Float16* vout = v + ((size_t)(b*DIM + c)*HIM + y0)*WIM + xg*8;

    #pragma unroll
    for (int y = 0; y < 8; ++y) {
        float acc[8];
        #pragma unroll
        for (int j = 0; j < 8; ++j) acc[j] = bias;
        #pragma unroll
        for (int cin = 0; cin < CIN; ++cin) {
            #pragma unroll
            for (int dy = 0; dy < 3; ++dy) {
                const float* rowp = &xs[cin][y+dy][xg*8];
                float4 f0 = *(const float4*)(rowp);
                float4 f1 = *(const float4*)(rowp + 4);
                float4 f2 = *(const float4*)(rowp + 8);
                float4 f3 = *(const float4*)(rowp + 12);
                float rr16[16] = {f0.x,f0.y,f0.z,f0.w, f1.x,f1.y,f1.z,f1.w,
                                  f2.x,f2.y,f2.z,f2.w, f3.x,f3.y,f3.z,f3.w};
                const float* w3 = &w[cin*9 + dy*3];
                #pragma unroll
                for (int j = 0; j < 8; ++j)
                    acc[j] += w3[0]*rr16[j+3] + w3[1]*rr16[j+4] + w3[2]*rr16[j+5];
            }
        }
        half8 ov;
        #pragma unroll
        for (int j = 0; j < 8; ++j) ov[j] = (_Float16)acc[j];
        *(half8*)(vout + y*WIM) = ov;
    }
}

// ------------- w16 = fp16(proj_w) ------------------------------------------
__global__ __launch_bounds__(256) void k_wcast(const float* __restrict__ pw,
        _Float16* __restrict__ w16)
{
    int i = blockIdx.x*256 + threadIdx.x;              // 65536
    w16[i] = (_Float16)pw[i];
}

// ------------- xe[b,n,c] = patch-embed conv (stride 16) + pb ---------------
__global__ __launch_bounds__(256) void k_patch(const float* __restrict__ x,
        const float* __restrict__ pw, const float* __restrict__ pb,
        float* __restrict__ xe)
{
    __shared__ __align__(16) float px[CIN*PS*PS];
    int b = blockIdx.x / NP, n = blockIdx.x % NP;
    int hp = n / WP, wp = n % WP;
    for (int i = threadIdx.x; i < CIN*PS*PS; i += 256) {
        int cin = i >> 8, rem = i & 255;
        int ki = rem >> 4, kj = rem & 15;
        px[i] = x[((size_t)(b*CIN + cin)*HIM + hp*PS + ki)*WIM + wp*PS + kj];
    }
    __syncthreads();
    int c = threadIdx.x;
    const float* wrow = pw + (size_t)c * (CIN*PS*PS);
    float acc = pb[c];
    for (int i = 0; i < CIN*PS*PS; i += 4) {
        float4 wv = *(const float4*)(wrow + i);
        float4 xv = *(const float4*)(px + i);
        acc += wv.x*xv.x + wv.y*xv.y + wv.z*xv.z + wv.w*xv.w;
    }
    xe[(size_t)(b*NP + n)*DIM + c] = acc;
}

// ---- q,k [bh, n, 32] = xe @ qk_w^T split ----------------------------------
__global__ __launch_bounds__(512) void k_qk(const float* __restrict__ xe,
        const float* __restrict__ qkw, float* __restrict__ q, float* __restrict__ kk)
{
    __shared__ __align__(16) float xr[DIM];
    int bn = blockIdx.x;
    for (int i = threadIdx.x; i < DIM; i += 512) xr[i] = xe[(size_t)bn*DIM + i];
    __syncthreads();
    int j = threadIdx.x;
    const float* wrow = qkw + (size_t)j * DIM;
    float acc = 0.f;
    for (int i = 0; i < DIM; i += 4) {
        float4 wv = *(const float4*)(wrow + i);
        float4 xv = *(const float4*)(xr + i);
        acc += wv.x*xv.x + wv.y*xv.y + wv.z*xv.z + wv.w*xv.w;
    }
    int s = j >> 8, h = (j >> 5) & 7, d = j & 31;
    int b = bn / NP, n = bn % NP;
    float* dst = s ? kk : q;
    dst[((size_t)(b*HEADS + h)*NP + n)*HD + d] = acc;
}

// ---- attn fp16 padded [bh][208][224]; cols 196..223 = 0 -------------------
__global__ __launch_bounds__(256) void k_attn(const float* __restrict__ q,
        const float* __restrict__ kk, _Float16* __restrict__ attnp)
{
    int wid = threadIdx.x >> 6, lane = threadIdx.x & 63;
    int row = blockIdx.x * 4 + wid;                    // [0, 6272)
    int bh = row / NP, n = row % NP;
    const float* qrow = q + (size_t)row * HD;
    float qr[HD];
    #pragma unroll
    for (int i = 0; i < HD; ++i) qr[i] = qrow[i];
    const float* kbase = kk + (size_t)bh * NP * HD;
    float s[4];
    #pragma unroll
    for (int t = 0; t < 4; ++t) {
        int m = lane + t*64;
        if (m < NP) {
            const float* krow = kbase + (size_t)m * HD;
            float a = 0.f;
            #pragma unroll
            for (int i = 0; i < HD; ++i) a += qr[i]*krow[i];
            s[t] = a * 0.17677669529663689f;
        } else s[t] = -1e30f;
    }
    float mx = fmaxf(fmaxf(s[0], s[1]), fmaxf(s[2], s[3]));
    #pragma unroll
    for (int off = 32; off > 0; off >>= 1) mx = fmaxf(mx, __shfl_xor(mx, off));
    float e[4]; float sum = 0.f;
    #pragma unroll
    for (int t = 0; t < 4; ++t) { e[t] = __expf(s[t] - mx); sum += e[t]; }
    #pragma unroll
    for (int off = 32; off > 0; off >>= 1) sum += __shfl_xor(sum, off);
    float inv = 1.f / sum;
    _Float16* arow = attnp + ((size_t)bh*NPAD + n)*KPAD;
    #pragma unroll
    for (int t = 0; t < 4; ++t) {
        int m = lane + t*64;
        if (m < KPAD) arow[m] = (m < NP) ? (_Float16)(e[t]*inv) : (_Float16)0.f;
    }
}

// ------ mix = fold( attn @ unfold(v) ) fp16 [b][c][pix], MFMA f16 ----------
// block = (bh, dblk of 128 N-cols). c = 32h + dblk/2, p0 = (dblk&1)*128.
// M=208(n) x N=128(p) x K=224(m).
__global__ __launch_bounds__(256) void k_av(const _Float16* __restrict__ attnp,
        const _Float16* __restrict__ vh, _Float16* __restrict__ mix)
{
    __shared__ __align__(16) _Float16 As[NPAD][40];    // 16.6 KB, pad 40 (2-way free)
    __shared__ __align__(16) _Float16 Vs[32][132];     // 8.4 KB, m-major
    int gid = blockIdx.x;
    int dblk = gid & 63, bh = gid >> 6;
    int b = bh >> 3, h = bh & 7;
    int c = h*HD + (dblk >> 1);
    int p0 = (dblk & 1) * 128;
    int t = threadIdx.x;
    int w = t >> 6, lane = t & 63, lg = lane >> 4, lr = lane & 15;

    f32x4 acc[13][2];
    #pragma unroll
    for (int i = 0; i < 13; ++i) {
        acc[i][0] = (f32x4){0.f,0.f,0.f,0.f};
        acc[i][1] = (f32x4){0.f,0.f,0.f,0.f};
    }
    const _Float16* abase = attnp + (size_t)bh * NPAD * KPAD;
    const _Float16* vbase = vh + (size_t)(b*DIM + c) * PIXN;

    for (int ks = 0; ks < 7; ++ks) {
        int k0 = ks*32;
        __syncthreads();
        for (int i = t; i < NPAD*4; i += 256) {        // A chunk [208][32]
            int row = i >> 2, ko = (i & 3)*8;
            *(half8*)&As[row][ko] = *(const half8*)(abase + (size_t)row*KPAD + k0 + ko);
        }
        for (int i = t; i < 512; i += 256) {           // V chunk [32 m][128 p]
            int mr = i >> 4;
            int m = k0 + mr; if (m > 195) m = 195;     // pad rows: finite, A=0 there
            int pj = (i & 15) * 8;
            int p = p0 + pj;
            int y = (m/WP)*PS + (p >> 4);
            int xx = (m%WP)*PS + (p & 15);
            half8 vv = *(const half8*)(vbase + (size_t)y*WIM + xx);
            *(half4v*)&Vs[mr][pj]   = (half4v){vv[0],vv[1],vv[2],vv[3]};
            *(half4v*)&Vs[mr][pj+4] = (half4v){vv[4],vv[5],vv[6],vv[7]};
        }
        __syncthreads();
        half8 bf0, bf1;
        int col0 = (w*2+0)*16 + lr, col1 = (w*2+1)*16 + lr;
        #pragma unroll
        for (int j = 0; j < 8; ++j) {
            bf0[j] = Vs[lg*8 + j][col0];
            bf1[j] = Vs[lg*8 + j][col1];
        }
        #pragma unroll
        for (int fr = 0; fr < 13; ++fr) {
            half8 afr = *(const half8*)&As[fr*16 + lr][lg*8];
            acc[fr][0] = __builtin_amdgcn_mfma_f32_16x16x32_f16(afr, bf0, acc[fr][0], 0,0,0);
            acc[fr][1] = __builtin_amdgcn_mfma_f32_16x16x32_f16(afr, bf1, acc[fr][1], 0,0,0);
        }
    }
    _Float16* mbase = mix + (size_t)(b*DIM + c) * PIXN;
    #pragma unroll
    for (int fr = 0; fr < 13; ++fr) {
        #pragma unroll
        for (int fc = 0; fc < 2; ++fc) {
            int p = p0 + (w*2+fc)*16 + lr;
            int ki = p >> 4, kj = p & 15;
            #pragma unroll
            for (int r = 0; r < 4; ++r) {
                int n = fr*16 + lg*4 + r;
                if (n < NP) {
                    int y = (n/WP)*PS + ki, xx = (n%WP)*PS + kj;
                    mbase[(size_t)y*WIM + xx] = (_Float16)acc[fr][fc][r];
                }
            }
        }
    }
}

// ------- out[b,co,px] = W16[co,:] @ mix[b,:,px] + pb, MFMA f16, fp32 out ---
// block = (b, mb of 128 co, nb of 128 px). K = 256 in 8 steps.
__global__ __launch_bounds__(256) void k_proj(const _Float16* __restrict__ w16,
        const float* __restrict__ pb, const _Float16* __restrict__ mix,
        float* __restrict__ out)
{
    __shared__ __align__(16) _Float16 Ws[128][40];     // 10.2 KB
    __shared__ __align__(16) _Float16 Xs[32][132];     // 8.4 KB
    int gid = blockIdx.x;
    int nb = gid % 392; gid /= 392;
    int mb = gid & 1; int b = gid >> 1;
    int px0 = nb * 128;
    int t = threadIdx.x;
    int w = t >> 6, lane = t & 63, lg = lane >> 4, lr = lane & 15;

    f32x4 acc[8][2];
    #pragma unroll
    for (int i = 0; i < 8; ++i) {
        acc[i][0] = (f32x4){0.f,0.f,0.f,0.f};
        acc[i][1] = (f32x4){0.f,0.f,0.f,0.f};
    }
    const _Float16* wbase = w16 + (size_t)mb*128*DIM;
    const _Float16* xbase = mix + (size_t)b*DIM*PIXN + px0;

    for (int ks = 0; ks < 8; ++ks) {
        int k0 = ks*32;
        __syncthreads();
        for (int i = t; i < 512; i += 256) {           // W chunk [128 co][32 c]
            int row = i >> 2, ko = (i & 3)*8;
            *(half8*)&Ws[row][ko] = *(const half8*)(wbase + (size_t)row*DIM + k0 + ko);
        }
        for (int i = t; i < 512; i += 256) {           // X chunk [32 c][128 px]
            int cr = i >> 4;
            int pj = (i & 15) * 8;
            half8 vv = *(const half8*)(xbase + (size_t)(k0+cr)*PIXN + pj);
            *(half4v*)&Xs[cr][pj]   = (half4v){vv[0],vv[1],vv[2],vv[3]};
            *(half4v*)&Xs[cr][pj+4] = (half4v){vv[4],vv[5],vv[6],vv[7]};
        }
        __syncthreads();
        half8 bf0, bf1;
        int col0 = (w*2+0)*16 + lr, col1 = (w*2+1)*16 + lr;
        #pragma unroll
        for (int j = 0; j < 8; ++j) {
            bf0[j] = Xs[lg*8 + j][col0];
            bf1[j] = Xs[lg*8 + j][col1];
        }
        #pragma unroll
        for (int fr = 0; fr < 8; ++fr) {
            half8 afr = *(const half8*)&Ws[fr*16 + lr][lg*8];
            acc[fr][0] = __builtin_amdgcn_mfma_f32_16x16x32_f16(afr, bf0, acc[fr][0], 0,0,0);
            acc[fr][1] = __builtin_amdgcn_mfma_f32_16x16x32_f16(afr, bf1, acc[fr][1], 0,0,0);
        }
    }
    #pragma unroll
    for (int fr = 0; fr < 8; ++fr) {
        #pragma unroll
        for (int fc = 0; fc < 2; ++fc) {
            int px = px0 + (w*2+fc)*16 + lr;
            #pragma unroll
            for (int r = 0; r < 4; ++r) {
                int co = mb*128 + fr*16 + lg*4 + r;
                out[(size_t)(b*DIM + co)*PIXN + px] = acc[fr][fc][r] + pb[co];
            }
        }
    }
}

extern "C" void kernel_launch(void* const* d_in, const int* in_sizes, int n_in,
                              void* d_out, int out_size, void* d_ws, size_t ws_size,
                              hipStream_t stream)
{
    const float* x   = (const float*)d_in[0];
    const float* pw  = (const float*)d_in[1];
    const float* pbb = (const float*)d_in[2];
    const float* qkw = (const float*)d_in[3];
    const float* vw  = (const float*)d_in[4];
    const float* vb  = (const float*)d_in[5];
    const float* prw = (const float*)d_in[6];
    const float* prb = (const float*)d_in[7];
    float* out = (float*)d_out;

    const size_t n_vh   = (size_t)BB*DIM*PIXN;             // 51,380,224 half
    const size_t n_attn = (size_t)BB*HEADS*NPAD*KPAD;      // 1,490,944 half
    const size_t n_w16  = (size_t)DIM*DIM;                 // 65,536 half
    const size_t n_xe   = (size_t)BB*NP*DIM;               // float
    const size_t n_qk   = (size_t)BB*HEADS*NP*HD;          // float

    size_t need = n_vh*2 + n_vh*2 + n_attn*2 + n_w16*2 + (n_xe + 2*n_qk)*4;
    if (ws_size < need) return;

    char* p = (char*)d_ws;
    _Float16* vh   = (_Float16*)p; p += n_vh*2;
    _Float16* mixh = (_Float16*)p; p += n_vh*2;
    _Float16* attp = (_Float16*)p; p += n_attn*2;
    _Float16* w16  = (_Float16*)p; p += n_w16*2;
    float* xe = (float*)p; p += n_xe*4;
    float* q  = (float*)p; p += n_qk*4;
    float* kk = (float*)p; p += n_qk*4;

    hipLaunchKernelGGL(k_vconv, dim3(3584), dim3(256), 0, stream, x, vw, vb, vh);
    hipLaunchKernelGGL(k_wcast, dim3(256),  dim3(256), 0, stream, prw, w16);
    hipLaunchKernelGGL(k_patch, dim3(784),  dim3(256), 0, stream, x, pw, pbb, xe);
    hipLaunchKernelGGL(k_qk,    dim3(784),  dim3(512), 0, stream, xe, qkw, q, kk);
    hipLaunchKernelGGL(k_attn,  dim3(1568), dim3(256), 0, stream, q, kk, attp);
    hipLaunchKernelGGL(k_av,    dim3(2048), dim3(256), 0, stream, attp, vh, mixh);
    hipLaunchKernelGGL(k_proj,  dim3(3136), dim3(256), 0, stream, w16, prb, mixh, out);
}